// Round 4
// baseline (2471.012 us; speedup 1.0000x reference)
//
#include <hip/hip_runtime.h>
#include <math.h>

#define NN 100000
#define NR 8
#define NE 640000
#define SEGN (NN * NR)                 // 800000
#define SPB 2048                       // segments per scan block
#define NSB ((SEGN + SPB - 1) / SPB)   // 391

// ---------------- preprocessing: CSR by (rel, dst) ----------------
// seg = rel * NN + dst  -> edges of a node-tile for fixed rel are CONTIGUOUS.

__global__ __launch_bounds__(256) void count_kernel(
    const int* __restrict__ dst, const int* __restrict__ et, unsigned* __restrict__ cnt) {
    int e = blockIdx.x * 256 + threadIdx.x;
    if (e < NE) atomicAdd(&cnt[(size_t)et[e] * NN + dst[e]], 1u);
}

__global__ __launch_bounds__(256) void scan1_kernel(
    const unsigned* __restrict__ cnt, unsigned* __restrict__ bsum) {
    __shared__ unsigned red[256];
    int b = blockIdx.x, t = threadIdx.x;
    int i0 = b * SPB;
    unsigned s = 0;
#pragma unroll
    for (int k = 0; k < SPB / 256; ++k) {
        int i = i0 + k * 256 + t;
        if (i < SEGN) s += cnt[i];
    }
    red[t] = s;
    __syncthreads();
    for (int off = 128; off >= 1; off >>= 1) {
        if (t < off) red[t] += red[t + off];
        __syncthreads();
    }
    if (t == 0) bsum[b] = red[0];
}

__global__ __launch_bounds__(512) void scan2_kernel(
    unsigned* __restrict__ bsum, int* __restrict__ segoff) {
    __shared__ unsigned buf[512];
    int t = threadIdx.x;
    unsigned v = (t < NSB) ? bsum[t] : 0u;
    buf[t] = v;
    __syncthreads();
    for (int off = 1; off < 512; off <<= 1) {
        unsigned w = (t >= off) ? buf[t - off] : 0u;
        __syncthreads();
        buf[t] += w;
        __syncthreads();
    }
    if (t < NSB) bsum[t] = buf[t] - v;   // exclusive block offsets
    if (t == 0) segoff[SEGN] = NE;
}

__global__ __launch_bounds__(256) void scan3_kernel(
    const unsigned* __restrict__ cnt, const unsigned* __restrict__ bsum,
    int* __restrict__ segoff) {
    __shared__ unsigned lc[SPB];      // 8 KB
    __shared__ unsigned tsum[256];
    int b = blockIdx.x, t = threadIdx.x;
    int i0 = b * SPB;
#pragma unroll
    for (int k = 0; k < SPB / 256; ++k) {
        int i = i0 + k * 256 + t;
        lc[k * 256 + t] = (i < SEGN) ? cnt[i] : 0u;
    }
    __syncthreads();
    unsigned s = 0;
#pragma unroll
    for (int k = 0; k < 8; ++k) s += lc[t * 8 + k];
    tsum[t] = s;
    __syncthreads();
    for (int off = 1; off < 256; off <<= 1) {
        unsigned w = (t >= off) ? tsum[t - off] : 0u;
        __syncthreads();
        tsum[t] += w;
        __syncthreads();
    }
    unsigned base = bsum[b] + tsum[t] - s;   // exclusive prefix for this thread's 8
#pragma unroll
    for (int k = 0; k < 8; ++k) {
        unsigned c = lc[t * 8 + k];
        lc[t * 8 + k] = base;
        base += c;
    }
    __syncthreads();
#pragma unroll
    for (int k = 0; k < SPB / 256; ++k) {
        int i = i0 + k * 256 + t;
        if (i < SEGN) segoff[i] = (int)lc[k * 256 + t];
    }
}

__global__ __launch_bounds__(256) void fill_kernel(
    const int* __restrict__ src, const int* __restrict__ dst, const int* __restrict__ et,
    const int* __restrict__ segoff, unsigned* __restrict__ cursor,
    const unsigned* __restrict__ cnt,
    int* __restrict__ esrc, int* __restrict__ edst, float* __restrict__ einv) {
    int e = blockIdx.x * 256 + threadIdx.x;
    if (e >= NE) return;
    int d = dst[e];
    int seg = et[e] * NN + d;
    int pos = segoff[seg] + (int)atomicAdd(&cursor[seg], 1u);
    esrc[pos] = src[e];
    edst[pos] = d;
    einv[pos] = 1.0f / (float)cnt[seg];
}

// ---------------- fused layer: edge-parallel gather + 9-way GEMM + epilogue ----
// r = 0..7: saggT[:,j] = mean_{edges of (n0+j, r)} x[src]   (LDS f32 atomics)
// r = 8   : saggT[:,j] = x[n0+j]                             (root term, Wr)
// epilogue: + bias, MODE 0: relu+LN; 1: relu+resid+LN; 2: relu; 3: plain

template <int D, int O, int MODE>
__global__ __launch_bounds__(256) void fused_layer(
    const float* __restrict__ x, const float* __restrict__ W, const float* __restrict__ Wr,
    const float* __restrict__ bias, const float* __restrict__ gamma, const float* __restrict__ beta,
    const int* __restrict__ segoff, const int* __restrict__ esrc, const int* __restrict__ edst,
    const float* __restrict__ einv, float* __restrict__ out)
{
    constexpr int NT   = 64;
    constexpr int PADC = NT + 4;       // 68: float4-aligned column blocks
    constexpr int TO   = O / 4;        // 32 (O=128) or 16 (O=64)
    constexpr int TJ   = 256 / TO;     // 8 or 16
    constexpr int NPT  = NT / TJ;      // 8 or 4 nodes per thread

    __shared__ float saggT[D][PADC];
    __shared__ float sW[32 * O];

    int t  = threadIdx.x;
    int to = t % TO, tj = t / TO;
    int n0 = blockIdx.x * NT;
    int wv = t >> 6, ln = t & 63;
    int nclamp = (NN - n0 < NT) ? (NN - n0) : NT;

    float racc[NPT][4];
#pragma unroll
    for (int m = 0; m < NPT; ++m)
#pragma unroll
        for (int q = 0; q < 4; ++q) racc[m][q] = 0.0f;

    for (int r = 0; r <= NR; ++r) {
        int e0 = 0, e1 = 0;
        if (r < NR) {
            int segbase = r * NN + n0;
            e0 = segoff[segbase];
            e1 = segoff[segbase + nclamp];
            if (e0 == e1) continue;    // no edges for this (tile, rel): contributes 0
        }
        __syncthreads();               // previous GEMM done reading saggT
        for (int idx = t; idx < D * PADC; idx += 256) (&saggT[0][0])[idx] = 0.0f;
        __syncthreads();

        if (r < NR) {
            // edge-parallel gather: waves stride the contiguous edge range
            int e = e0 + wv;
            for (; e + 4 < e1; e += 8) {   // 2-deep pipeline: independent chains
                int sA = esrc[e],     sB = esrc[e + 4];
                int jA = edst[e] - n0, jB = edst[e + 4] - n0;
                float cA = einv[e],   cB = einv[e + 4];
                const float* xA = x + (size_t)sA * D;
                const float* xB = x + (size_t)sB * D;
                if (D == 128) {
                    float2 vA = *(const float2*)&xA[2 * ln];
                    float2 vB = *(const float2*)&xB[2 * ln];
                    atomicAdd(&saggT[2 * ln][jA],     vA.x * cA);
                    atomicAdd(&saggT[2 * ln + 1][jA], vA.y * cA);
                    atomicAdd(&saggT[2 * ln][jB],     vB.x * cB);
                    atomicAdd(&saggT[2 * ln + 1][jB], vB.y * cB);
                } else {
                    float vA = xA[ln], vB = xB[ln];
                    atomicAdd(&saggT[ln][jA], vA * cA);
                    atomicAdd(&saggT[ln][jB], vB * cB);
                }
            }
            if (e < e1) {
                int sA = esrc[e];
                int jA = edst[e] - n0;
                float cA = einv[e];
                const float* xA = x + (size_t)sA * D;
                if (D == 128) {
                    float2 vA = *(const float2*)&xA[2 * ln];
                    atomicAdd(&saggT[2 * ln][jA],     vA.x * cA);
                    atomicAdd(&saggT[2 * ln + 1][jA], vA.y * cA);
                } else {
                    atomicAdd(&saggT[ln][jA], xA[ln] * cA);
                }
            }
        } else {
            // root: direct tile load
            for (int j = wv; j < nclamp; j += 4) {
                const float* xp = x + (size_t)(n0 + j) * D;
                if (D == 128) {
                    float2 v = *(const float2*)&xp[2 * ln];
                    saggT[2 * ln][j]     = v.x;
                    saggT[2 * ln + 1][j] = v.y;
                } else {
                    saggT[ln][j] = xp[ln];
                }
            }
        }

        const float* Wsel = (r < NR) ? (W + (size_t)r * D * O) : Wr;
        for (int kc = 0; kc < D; kc += 32) {
            __syncthreads();           // saggT ready / prev chunk done with sW
            for (int idx = t; idx < 32 * O; idx += 256) sW[idx] = Wsel[(size_t)kc * O + idx];
            __syncthreads();
#pragma unroll 8
            for (int ii = 0; ii < 32; ++ii) {
                float4 b4 = *(const float4*)&sW[ii * O + to * 4];
#define FMA4(m, a) \
                racc[m][0] += (a) * b4.x; racc[m][1] += (a) * b4.y; \
                racc[m][2] += (a) * b4.z; racc[m][3] += (a) * b4.w;
                if constexpr (NPT == 8) {
                    float4 a1 = *(const float4*)&saggT[kc + ii][tj * 8];
                    float4 a2 = *(const float4*)&saggT[kc + ii][tj * 8 + 4];
                    FMA4(0, a1.x) FMA4(1, a1.y) FMA4(2, a1.z) FMA4(3, a1.w)
                    FMA4(4, a2.x) FMA4(5, a2.y) FMA4(6, a2.z) FMA4(7, a2.w)
                } else {
                    float4 a1 = *(const float4*)&saggT[kc + ii][tj * 4];
                    FMA4(0, a1.x) FMA4(1, a1.y) FMA4(2, a1.z) FMA4(3, a1.w)
                }
#undef FMA4
            }
        }
    }

    // ---- epilogue ----
    float4 bb = *(const float4*)&bias[to * 4];
    float4 gg = make_float4(0, 0, 0, 0), be = make_float4(0, 0, 0, 0);
    if constexpr (MODE == 0 || MODE == 1) {
        gg = *(const float4*)&gamma[to * 4];
        be = *(const float4*)&beta[to * 4];
    }
#pragma unroll
    for (int m = 0; m < NPT; ++m) {
        int n = n0 + tj * NPT + m;
        bool valid = (n < NN);
        float v0 = racc[m][0] + bb.x;
        float v1 = racc[m][1] + bb.y;
        float v2 = racc[m][2] + bb.z;
        float v3 = racc[m][3] + bb.w;
        if constexpr (MODE <= 2) {
            v0 = fmaxf(v0, 0.0f); v1 = fmaxf(v1, 0.0f);
            v2 = fmaxf(v2, 0.0f); v3 = fmaxf(v3, 0.0f);
        }
        if constexpr (MODE == 1) {
            if (valid) {
                float4 xr = *(const float4*)&x[(size_t)n * D + to * 4];  // D==O==128
                v0 += xr.x; v1 += xr.y; v2 += xr.z; v3 += xr.w;
            }
        }
        if constexpr (MODE == 0 || MODE == 1) {
            // LN over O=128: the 32 consecutive lanes sharing tj hold one node's row
            float s1 = v0 + v1 + v2 + v3;
            float s2 = v0 * v0 + v1 * v1 + v2 * v2 + v3 * v3;
#pragma unroll
            for (int off = 1; off < 32; off <<= 1) {
                s1 += __shfl_xor(s1, off, 64);
                s2 += __shfl_xor(s2, off, 64);
            }
            float mu  = s1 * (1.0f / O);
            float var = s2 * (1.0f / O) - mu * mu;
            float rs  = rsqrtf(var + 1e-5f);
            v0 = (v0 - mu) * rs * gg.x + be.x;
            v1 = (v1 - mu) * rs * gg.y + be.y;
            v2 = (v2 - mu) * rs * gg.z + be.z;
            v3 = (v3 - mu) * rs * gg.w + be.w;
        }
        if (valid) {
            *(float4*)&out[(size_t)n * O + to * 4] = make_float4(v0, v1, v2, v3);
        }
    }
}

// ---------------- host launch ----------------

extern "C" void kernel_launch(void* const* d_in, const int* in_sizes, int n_in,
                              void* d_out, int out_size, void* d_ws, size_t ws_size,
                              hipStream_t stream) {
    const float* emb = (const float*)d_in[0];
    const float* W1  = (const float*)d_in[1];
    const float* R1  = (const float*)d_in[2];
    const float* B1  = (const float*)d_in[3];
    const float* W2  = (const float*)d_in[4];
    const float* R2  = (const float*)d_in[5];
    const float* B2  = (const float*)d_in[6];
    const float* W3  = (const float*)d_in[7];
    const float* R3  = (const float*)d_in[8];
    const float* B3  = (const float*)d_in[9];
    const float* W4  = (const float*)d_in[10];
    const float* R4  = (const float*)d_in[11];
    const float* B4  = (const float*)d_in[12];
    const float* g1  = (const float*)d_in[13];
    const float* b1  = (const float*)d_in[14];
    const float* g2  = (const float*)d_in[15];
    const float* b2  = (const float*)d_in[16];
    const int*   ei  = (const int*)d_in[17];
    const int*   et  = (const int*)d_in[18];
    const int* srcp = ei;
    const int* dstp = ei + NE;

    char* ws = (char*)d_ws;
    // layout (bytes):
    // cnt    u32[800000]        @ 0            (3,200,000)
    // segoff i32[800001]        @ 3,200,000    (pad to 3,200,016)
    // cursor u32[800000]        @ 6,400,016
    // bsum   u32[512]           @ 9,600,016    (pad to 9,602,080)
    // esrc   i32[640000]        @ 9,602,080
    // edst   i32[640000]        @ 12,162,080
    // einv   f32[640000]        @ 14,722,080
    // x1     f32[100000*128]    @ 17,282,080
    // x2     f32[100000*128]    @ 68,482,080
    // x3     f32[100000*64]     @ 119,682,080  end 145,282,080
    if (ws_size < 145282080u) return;
    unsigned* cnt    = (unsigned*)(ws + 0);
    int*      segoff = (int*)(ws + 3200000);
    unsigned* cursor = (unsigned*)(ws + 6400016);
    unsigned* bsum   = (unsigned*)(ws + 9600016);
    int*      esrc   = (int*)(ws + 9602080);
    int*      edst   = (int*)(ws + 12162080);
    float*    einv   = (float*)(ws + 14722080);
    float*    x1     = (float*)(ws + 17282080);
    float*    x2     = (float*)(ws + 68482080);
    float*    x3     = (float*)(ws + 119682080);
    float*    outp   = (float*)d_out;

    hipMemsetAsync(cnt, 0, 3200000, stream);
    hipMemsetAsync(cursor, 0, 3200000, stream);

    count_kernel<<<(NE + 255) / 256, 256, 0, stream>>>(dstp, et, cnt);
    scan1_kernel<<<NSB, 256, 0, stream>>>(cnt, bsum);
    scan2_kernel<<<1, 512, 0, stream>>>(bsum, segoff);
    scan3_kernel<<<NSB, 256, 0, stream>>>(cnt, bsum, segoff);
    fill_kernel<<<(NE + 255) / 256, 256, 0, stream>>>(
        srcp, dstp, et, segoff, cursor, cnt, esrc, edst, einv);

    const int GRID = (NN + 63) / 64;   // 1563
    // Layer 1: emb(64) -> x1(128), relu+LN
    fused_layer<64, 128, 0><<<GRID, 256, 0, stream>>>(
        emb, W1, R1, B1, g1, b1, segoff, esrc, edst, einv, x1);
    // Layer 2: x1(128) -> x2(128), relu+resid+LN
    fused_layer<128, 128, 1><<<GRID, 256, 0, stream>>>(
        x1, W2, R2, B2, g2, b2, segoff, esrc, edst, einv, x2);
    // Layer 3: x2(128) -> x3(64), relu
    fused_layer<128, 64, 2><<<GRID, 256, 0, stream>>>(
        x2, W3, R3, B3, nullptr, nullptr, segoff, esrc, edst, einv, x3);
    // Layer 4: x3(64) -> out(64), plain
    fused_layer<64, 64, 3><<<GRID, 256, 0, stream>>>(
        x3, W4, R4, B4, nullptr, nullptr, segoff, esrc, edst, einv, outp);
}

// Round 5
// 1716.230 us; speedup vs baseline: 1.4398x; 1.4398x over previous
//
#include <hip/hip_runtime.h>
#include <math.h>

#define NN 100000
#define NR 8
#define NE 640000
#define SEGN (NN * NR)                 // 800000
#define SPB 2048                       // segments per scan block
#define NSB ((SEGN + SPB - 1) / SPB)   // 391

typedef __attribute__((ext_vector_type(8))) __bf16 bf16x8;
typedef __attribute__((ext_vector_type(4))) float  f32x4;

// ---------------- preprocessing: CSR by (rel, dst) ----------------
// seg = rel * NN + dst  -> edges of a node-tile for fixed rel are CONTIGUOUS.

__global__ __launch_bounds__(256) void count_kernel(
    const int* __restrict__ dst, const int* __restrict__ et, unsigned* __restrict__ cnt) {
    int e = blockIdx.x * 256 + threadIdx.x;
    if (e < NE) atomicAdd(&cnt[(size_t)et[e] * NN + dst[e]], 1u);
}

__global__ __launch_bounds__(256) void scan1_kernel(
    const unsigned* __restrict__ cnt, unsigned* __restrict__ bsum) {
    __shared__ unsigned red[256];
    int b = blockIdx.x, t = threadIdx.x;
    int i0 = b * SPB;
    unsigned s = 0;
#pragma unroll
    for (int k = 0; k < SPB / 256; ++k) {
        int i = i0 + k * 256 + t;
        if (i < SEGN) s += cnt[i];
    }
    red[t] = s;
    __syncthreads();
    for (int off = 128; off >= 1; off >>= 1) {
        if (t < off) red[t] += red[t + off];
        __syncthreads();
    }
    if (t == 0) bsum[b] = red[0];
}

__global__ __launch_bounds__(512) void scan2_kernel(
    unsigned* __restrict__ bsum, int* __restrict__ segoff) {
    __shared__ unsigned buf[512];
    int t = threadIdx.x;
    unsigned v = (t < NSB) ? bsum[t] : 0u;
    buf[t] = v;
    __syncthreads();
    for (int off = 1; off < 512; off <<= 1) {
        unsigned w = (t >= off) ? buf[t - off] : 0u;
        __syncthreads();
        buf[t] += w;
        __syncthreads();
    }
    if (t < NSB) bsum[t] = buf[t] - v;   // exclusive block offsets
    if (t == 0) segoff[SEGN] = NE;
}

__global__ __launch_bounds__(256) void scan3_kernel(
    const unsigned* __restrict__ cnt, const unsigned* __restrict__ bsum,
    int* __restrict__ segoff) {
    __shared__ unsigned lc[SPB];
    __shared__ unsigned tsum[256];
    int b = blockIdx.x, t = threadIdx.x;
    int i0 = b * SPB;
#pragma unroll
    for (int k = 0; k < SPB / 256; ++k) {
        int i = i0 + k * 256 + t;
        lc[k * 256 + t] = (i < SEGN) ? cnt[i] : 0u;
    }
    __syncthreads();
    unsigned s = 0;
#pragma unroll
    for (int k = 0; k < 8; ++k) s += lc[t * 8 + k];
    tsum[t] = s;
    __syncthreads();
    for (int off = 1; off < 256; off <<= 1) {
        unsigned w = (t >= off) ? tsum[t - off] : 0u;
        __syncthreads();
        tsum[t] += w;
        __syncthreads();
    }
    unsigned base = bsum[b] + tsum[t] - s;
#pragma unroll
    for (int k = 0; k < 8; ++k) {
        unsigned c = lc[t * 8 + k];
        lc[t * 8 + k] = base;
        base += c;
    }
    __syncthreads();
#pragma unroll
    for (int k = 0; k < SPB / 256; ++k) {
        int i = i0 + k * 256 + t;
        if (i < SEGN) segoff[i] = (int)lc[k * 256 + t];
    }
}

__global__ __launch_bounds__(256) void fill_kernel(
    const int* __restrict__ src, const int* __restrict__ dst, const int* __restrict__ et,
    const int* __restrict__ segoff, unsigned* __restrict__ cursor,
    const unsigned* __restrict__ cnt, int4* __restrict__ emeta) {
    int e = blockIdx.x * 256 + threadIdx.x;
    if (e >= NE) return;
    int d = dst[e];
    int seg = et[e] * NN + d;
    int pos = segoff[seg] + (int)atomicAdd(&cursor[seg], 1u);
    float invc = 1.0f / (float)cnt[seg];
    emeta[pos] = make_int4(src[e], d, __float_as_int(invc), 0);
}

// ---------------- weight pack: f32 -> bf16 in MFMA B-fragment order -------
// Wp block for (r,kt,nt): 64 lanes x 8 bf16.  Lane l holds
// B[k = kt*32 + (l>>4)*8 + j][n = nt*16 + (l&15)], j=0..7.
// (A uses the same k-bijection, so the MFMA k-sum pairs correctly.)

template <int D, int O>
__global__ __launch_bounds__(256) void pack_kernel(
    const float* __restrict__ W, const float* __restrict__ Wr, __bf16* __restrict__ Wp) {
    constexpr int KT = D / 32, NTN = O / 16;
    int idx = blockIdx.x * 256 + threadIdx.x;
    if (idx >= (NR + 1) * KT * NTN * 64) return;
    int l = idx & 63;
    int rest = idx >> 6;
    int nt = rest % NTN; rest /= NTN;
    int kt = rest % KT;
    int r  = rest / KT;
    const float* srcw = (r < NR) ? (W + (size_t)r * D * O) : Wr;
    int n  = nt * 16 + (l & 15);
    int k0 = kt * 32 + (l >> 4) * 8;
    bf16x8 v;
#pragma unroll
    for (int j = 0; j < 8; ++j) v[j] = (__bf16)srcw[(size_t)(k0 + j) * O + n];
    *(bf16x8*)(Wp + (size_t)idx * 8) = v;
}

// ---------------- fused layer: gather + 9-way MFMA GEMM + epilogue ----------
// r = 0..7: saggT[:,j] = mean_{edges of (n0+j, r)} x[src]   (LDS f32 atomics)
// r = 8   : saggT[:,j] = x[n0+j]                             (root term)
// MODE 0: relu+LN; 1: relu+resid+LN; 2: relu; 3: plain

template <int D, int O, int MODE>
__global__ __launch_bounds__(256) void fused_layer(
    const float* __restrict__ x, const __bf16* __restrict__ Wp,
    const float* __restrict__ bias, const float* __restrict__ gamma,
    const float* __restrict__ beta, const int* __restrict__ segoff,
    const int4* __restrict__ emeta, float* __restrict__ out)
{
    constexpr int NT = 64, PADC = 65;
    constexpr int KT = D / 32, NTN = O / 16;

    __shared__ float saggT[D][PADC];   // dim-major agg tile (f32)

    int t  = threadIdx.x;
    int wv = t >> 6, ln = t & 63;
    int lg = ln >> 4, lm = ln & 15;
    int n0 = blockIdx.x * NT;
    int nclamp = (NN - n0 < NT) ? (NN - n0) : NT;

    f32x4 acc[NTN];
#pragma unroll
    for (int nt = 0; nt < NTN; ++nt)
#pragma unroll
        for (int q = 0; q < 4; ++q) acc[nt][q] = 0.0f;

    for (int r = 0; r <= NR; ++r) {
        int e0 = 0, e1 = 0;
        if (r < NR) {
            int segbase = r * NN + n0;
            e0 = segoff[segbase];
            e1 = segoff[segbase + nclamp];
            if (e0 == e1) continue;            // uniform across block
        }
        __syncthreads();                        // prev MFMA done reading saggT
        if (r < NR) {
            for (int idx = t; idx < D * PADC; idx += 256) (&saggT[0][0])[idx] = 0.0f;
            __syncthreads();
            // edge-parallel gather: waves stride the contiguous edge range
            for (int e = e0 + wv; e < e1; e += 4) {
                int4 m4 = emeta[e];
                int   j = m4.y - n0;
                float c = __int_as_float(m4.z);
                const float* xp = x + (size_t)m4.x * D;
                atomicAdd(&saggT[ln][j], xp[ln] * c);
                if constexpr (D == 128) atomicAdd(&saggT[ln + 64][j], xp[ln + 64] * c);
            }
        } else {
            // root: direct tile load
            for (int j = wv; j < nclamp; j += 4) {
                const float* xp = x + (size_t)(n0 + j) * D;
                saggT[ln][j] = xp[ln];
                if constexpr (D == 128) saggT[ln + 64][j] = xp[ln + 64];
            }
        }
        __syncthreads();                        // saggT ready

        // ---- MFMA phase: wave wv computes rows [wv*16, wv*16+16) ----
#pragma unroll
        for (int kt = 0; kt < KT; ++kt) {
            bf16x8 A;
#pragma unroll
            for (int j = 0; j < 8; ++j)
                A[j] = (__bf16)saggT[kt * 32 + lg * 8 + j][wv * 16 + lm];
            const __bf16* bp = Wp + ((size_t)((r * KT + kt) * NTN) << 9) + (ln << 3);
#pragma unroll
            for (int nt = 0; nt < NTN; ++nt) {
                bf16x8 B = *(const bf16x8*)(bp + ((size_t)nt << 9));
                acc[nt] = __builtin_amdgcn_mfma_f32_16x16x32_bf16(A, B, acc[nt], 0, 0, 0);
            }
        }
    }

    // ---- epilogue (C/D layout: col = nt*16+lm, row = lg*4+q within wave slab) ----
    float bb[NTN], gg[NTN], be[NTN];
#pragma unroll
    for (int nt = 0; nt < NTN; ++nt) {
        bb[nt] = bias[nt * 16 + lm];
        if constexpr (MODE <= 1) {
            gg[nt] = gamma[nt * 16 + lm];
            be[nt] = beta[nt * 16 + lm];
        } else {
            gg[nt] = 0.0f; be[nt] = 0.0f;
        }
    }
#pragma unroll
    for (int q = 0; q < 4; ++q) {
        int row = wv * 16 + lg * 4 + q;
        int n = n0 + row;
        float v[NTN];
#pragma unroll
        for (int nt = 0; nt < NTN; ++nt) {
            v[nt] = acc[nt][q] + bb[nt];
            if constexpr (MODE <= 2) v[nt] = fmaxf(v[nt], 0.0f);
            if constexpr (MODE == 1) v[nt] += saggT[nt * 16 + lm][row];  // residual (root tile)
        }
        if constexpr (MODE <= 1) {
            float s1 = 0.0f, s2 = 0.0f;
#pragma unroll
            for (int nt = 0; nt < NTN; ++nt) { s1 += v[nt]; s2 += v[nt] * v[nt]; }
#pragma unroll
            for (int off = 1; off < 16; off <<= 1) {
                s1 += __shfl_xor(s1, off, 64);
                s2 += __shfl_xor(s2, off, 64);
            }
            float mu  = s1 * (1.0f / O);
            float var = s2 * (1.0f / O) - mu * mu;
            float rs  = rsqrtf(var + 1e-5f);
#pragma unroll
            for (int nt = 0; nt < NTN; ++nt) v[nt] = (v[nt] - mu) * rs * gg[nt] + be[nt];
        }
        if (n < NN) {
#pragma unroll
            for (int nt = 0; nt < NTN; ++nt) out[(size_t)n * O + nt * 16 + lm] = v[nt];
        }
    }
}

// ---------------- host launch ----------------

extern "C" void kernel_launch(void* const* d_in, const int* in_sizes, int n_in,
                              void* d_out, int out_size, void* d_ws, size_t ws_size,
                              hipStream_t stream) {
    const float* emb = (const float*)d_in[0];
    const float* W1  = (const float*)d_in[1];
    const float* R1  = (const float*)d_in[2];
    const float* B1  = (const float*)d_in[3];
    const float* W2  = (const float*)d_in[4];
    const float* R2  = (const float*)d_in[5];
    const float* B2  = (const float*)d_in[6];
    const float* W3  = (const float*)d_in[7];
    const float* R3  = (const float*)d_in[8];
    const float* B3  = (const float*)d_in[9];
    const float* W4  = (const float*)d_in[10];
    const float* R4  = (const float*)d_in[11];
    const float* B4  = (const float*)d_in[12];
    const float* g1  = (const float*)d_in[13];
    const float* b1  = (const float*)d_in[14];
    const float* g2  = (const float*)d_in[15];
    const float* b2  = (const float*)d_in[16];
    const int*   ei  = (const int*)d_in[17];
    const int*   et  = (const int*)d_in[18];
    const int* srcp = ei;
    const int* dstp = ei + NE;

    char* ws = (char*)d_ws;
    // persistent layout (bytes):
    // segoff i32[800001]     @ 0            (pad to 3,200,016)
    // emeta  int4[640000]    @ 3,200,016    (10,240,000 -> 13,440,016)
    // Wp1    bf16[73728]     @ 13,440,016   (147,456 -> 13,587,472)
    // Wp2    bf16[147456]    @ 13,587,472   (294,912 -> 13,882,384)
    // Wp3    bf16[73728]     @ 13,882,384   (147,456 -> 14,029,840)
    // Wp4    bf16[36864]     @ 14,029,840   ( 73,728 -> 14,103,568)
    // x1     f32[12.8M]      @ 14,103,568   (51,200,000 -> 65,303,568)
    // x2     f32[12.8M]      @ 65,303,568   (51,200,000 -> 116,503,568)
    // x3     f32[6.4M]       @ 116,503,568  (25,600,000 -> 142,103,568)
    // transients (dead before x3 is written; aliased over x3 region):
    // cnt    u32[800000]     @ 116,503,568
    // cursor u32[800000]     @ 119,703,568
    // bsum   u32[512]        @ 122,903,568
    if (ws_size < 142103568u) return;
    int*      segoff = (int*)(ws + 0);
    int4*     emeta  = (int4*)(ws + 3200016);
    __bf16*   Wp1    = (__bf16*)(ws + 13440016);
    __bf16*   Wp2    = (__bf16*)(ws + 13587472);
    __bf16*   Wp3    = (__bf16*)(ws + 13882384);
    __bf16*   Wp4    = (__bf16*)(ws + 14029840);
    float*    x1     = (float*)(ws + 14103568);
    float*    x2     = (float*)(ws + 65303568);
    float*    x3     = (float*)(ws + 116503568);
    unsigned* cnt    = (unsigned*)(ws + 116503568);
    unsigned* cursor = (unsigned*)(ws + 119703568);
    unsigned* bsum   = (unsigned*)(ws + 122903568);
    float*    outp   = (float*)d_out;

    hipMemsetAsync(cnt, 0, 3200000, stream);
    hipMemsetAsync(cursor, 0, 3200000, stream);

    count_kernel<<<(NE + 255) / 256, 256, 0, stream>>>(dstp, et, cnt);
    scan1_kernel<<<NSB, 256, 0, stream>>>(cnt, bsum);
    scan2_kernel<<<1, 512, 0, stream>>>(bsum, segoff);
    scan3_kernel<<<NSB, 256, 0, stream>>>(cnt, bsum, segoff);
    fill_kernel<<<(NE + 255) / 256, 256, 0, stream>>>(
        srcp, dstp, et, segoff, cursor, cnt, emeta);

    pack_kernel<64, 128><<<(9 * 2 * 8 * 64 + 255) / 256, 256, 0, stream>>>(W1, R1, Wp1);
    pack_kernel<128, 128><<<(9 * 4 * 8 * 64 + 255) / 256, 256, 0, stream>>>(W2, R2, Wp2);
    pack_kernel<128, 64><<<(9 * 4 * 4 * 64 + 255) / 256, 256, 0, stream>>>(W3, R3, Wp3);
    pack_kernel<64, 64><<<(9 * 2 * 4 * 64 + 255) / 256, 256, 0, stream>>>(W4, R4, Wp4);

    const int GRID = (NN + 63) / 64;   // 1563
    fused_layer<64, 128, 0><<<GRID, 256, 0, stream>>>(
        emb, Wp1, B1, g1, b1, segoff, emeta, x1);
    fused_layer<128, 128, 1><<<GRID, 256, 0, stream>>>(
        x1, Wp2, B2, g2, b2, segoff, emeta, x2);
    fused_layer<128, 64, 2><<<GRID, 256, 0, stream>>>(
        x2, Wp3, B3, nullptr, nullptr, segoff, emeta, x3);
    fused_layer<64, 64, 3><<<GRID, 256, 0, stream>>>(
        x3, Wp4, B4, nullptr, nullptr, segoff, emeta, outp);
}